// Round 15
// baseline (2819.720 us; speedup 1.0000x reference)
//
#include <hip/hip_runtime.h>
#include <hip/hip_bf16.h>

typedef __hip_bfloat16 bf16;
typedef __attribute__((ext_vector_type(8))) __bf16 bf16x8;
typedef __attribute__((ext_vector_type(4))) float f32x4;

#define N_NODES 32768
#define N_EDGES 262144
#define DIM 768
#define NGR 64
#define KIN 800     // 784 padded to 32
#define KSTACK 6912 // self(768) + 8*768
#define NKEY (N_NODES * 8)

#define GLOBAL_AS __attribute__((address_space(1)))
#define LDS_AS __attribute__((address_space(3)))

__device__ __forceinline__ float gelu_f(float x) {
    return 0.5f * x * (1.0f + erff(x * 0.70710678118654752f));
}
__device__ __forceinline__ float bfu(unsigned short v) {
    union { unsigned u; float f; } x; x.u = (unsigned)v << 16; return x.f;
}
__device__ __forceinline__ unsigned short fbf(float f) {
    bf16 t = __float2bfloat16(f); return *(unsigned short*)&t;
}

// ---------------------------------------------------------------------------
// Transpose + cast fp32 [I][O] -> bf16 [O][ostride], zero-pad i in [I,Ipad)
__global__ __launch_bounds__(256)
void tcast_k(const float* __restrict__ in, bf16* __restrict__ out, int I, int O,
             int Ipad, int ostride) {
    __shared__ float t[32][33];
    const int i0 = blockIdx.x * 32, o0 = blockIdx.y * 32;
    const int tx = threadIdx.x & 31, ty = threadIdx.x >> 5;
#pragma unroll
    for (int q = 0; q < 4; ++q) {
        int i = i0 + ty + q * 8, o = o0 + tx;
        t[ty + q * 8][tx] = (i < I) ? in[(size_t)i * O + o] : 0.0f;
    }
    __syncthreads();
#pragma unroll
    for (int q = 0; q < 4; ++q) {
        int o = o0 + ty + q * 8, i = i0 + tx;
        if (i < Ipad) out[(size_t)o * ostride + i] = __float2bfloat16(t[tx][ty + q * 8]);
    }
}

// ---------------------------------------------------------------------------
// Per-layer weights -> WstL[768 out][6912 K], K order: [self | r0..r7]. grid(24,24,9)
__global__ __launch_bounds__(256)
void wprep_l_k(const float* __restrict__ Wrel_l, const float* __restrict__ Wloop_l,
               bf16* __restrict__ WstL) {
    __shared__ float t[32][33];
    const int q = blockIdx.z;
    const float* in = (q < 8) ? Wrel_l + (size_t)q * DIM * DIM : Wloop_l;
    bf16* out = WstL + (q < 8 ? (q + 1) * DIM : 0);
    const int i0 = blockIdx.x * 32, o0 = blockIdx.y * 32;
    const int tx = threadIdx.x & 31, ty = threadIdx.x >> 5;
#pragma unroll
    for (int qq = 0; qq < 4; ++qq)
        t[ty + qq * 8][tx] = in[(size_t)(i0 + ty + qq * 8) * DIM + o0 + tx];
    __syncthreads();
#pragma unroll
    for (int qq = 0; qq < 4; ++qq)
        out[(size_t)(o0 + ty + qq * 8) * KSTACK + i0 + tx] =
            __float2bfloat16(t[tx][ty + qq * 8]);
}

// ---------------------------------------------------------------------------
__global__ __launch_bounds__(256)
void concat_k(const float* __restrict__ tv, const float* __restrict__ cv, bf16* __restrict__ X) {
    const int n = blockIdx.x;
    for (int c = threadIdx.x; c < KIN; c += 256) {
        float v = 0.0f;
        if (c < 16) v = tv[(size_t)n * 16 + c];
        else if (c < 784) v = cv[(size_t)n * DIM + (c - 16)];
        X[(size_t)n * KIN + c] = __float2bfloat16(v);
    }
}

// ---------------------------------------------------------------------------
// CSR build over key = dst*8 + type. deg aliased into cur.
__global__ __launch_bounds__(256)
void hist2_k(const int* __restrict__ dst, const int* __restrict__ et, int* __restrict__ cur) {
    int e = blockIdx.x * 256 + threadIdx.x;
    if (e < N_EDGES) atomicAdd(&cur[dst[e] * 8 + et[e]], 1);
}

__global__ __launch_bounds__(1024)
void scan2_k(int* __restrict__ cur, int* __restrict__ rp) {
    __shared__ int part[1024];
    const int t = threadIdx.x;
    const int base_i = t * 256;
    int s = 0;
    for (int i = 0; i < 256; ++i) s += cur[base_i + i];
    part[t] = s; __syncthreads();
    for (int st = 1; st < 1024; st <<= 1) {
        int v = (t >= st) ? part[t - st] : 0;
        __syncthreads();
        part[t] += v;
        __syncthreads();
    }
    int run = part[t] - s;
    for (int i = 0; i < 256; ++i) {
        int d = cur[base_i + i];
        rp[base_i + i] = run; cur[base_i + i] = run;
        run += d;
    }
    if (t == 1023) rp[NKEY] = run;
}

__global__ __launch_bounds__(256)
void place2_k(const int* __restrict__ src, const int* __restrict__ dst,
              const int* __restrict__ et, int* __restrict__ cur,
              unsigned short* __restrict__ eidx) {
    int e = blockIdx.x * 256 + threadIdx.x;
    if (e >= N_EDGES) return;
    int pos = atomicAdd(&cur[dst[e] * 8 + et[e]], 1);
    eidx[pos] = (unsigned short)src[e];
}

// ---------------------------------------------------------------------------
// Gather-aggregate for NC relations [rbase, rbase+NC), exact CSR ranges.
template <int NC>
__global__ __launch_bounds__(256)
void gather8(const bf16* __restrict__ h, const int* __restrict__ rp2,
             const unsigned short* __restrict__ eidx, bf16* __restrict__ AGG,
             int rbase, int ostride, int colbase) {
    const int wave = threadIdx.x >> 6, lane = threadIdx.x & 63;
    const int n = blockIdx.x * 4 + wave;
    const int c0 = 4 * lane;
    unsigned short* outrow = (unsigned short*)&AGG[(size_t)n * ostride + colbase];
    const int* bp = &rp2[n * 8 + rbase];
    for (int sel = 0; sel < NC; ++sel) {
        const int s = bp[sel], e = bp[sel + 1];
        float f[12];
#pragma unroll
        for (int j = 0; j < 12; ++j) f[j] = 0.f;
        for (int t = s; t < e; ++t) {
            const unsigned short* hs = (const unsigned short*)&h[(size_t)eidx[t] * DIM];
#pragma unroll
            for (int j = 0; j < 3; ++j) {
                ushort4 u = *(const ushort4*)&hs[c0 + j * 256];
                f[4 * j + 0] += bfu(u.x); f[4 * j + 1] += bfu(u.y);
                f[4 * j + 2] += bfu(u.z); f[4 * j + 3] += bfu(u.w);
            }
        }
#pragma unroll
        for (int j = 0; j < 3; ++j) {
            ushort4 o;
            o.x = fbf(f[4 * j + 0]); o.y = fbf(f[4 * j + 1]);
            o.z = fbf(f[4 * j + 2]); o.w = fbf(f[4 * j + 3]);
            *(ushort4*)&outrow[sel * DIM + c0 + j * 256] = o;
        }
    }
}

// ---------------------------------------------------------------------------
// gemm192: C[M,Nn](bf16) =/+= A[M,K] @ BT[Nn,K]^T. BM=256, BN=192, BK=32.
// Partition chosen for 2 BLOCKS/CU: grid = nbx*(M/256) = 512 (vs 256 = 1/CU
// before -- the round-14 diagnosis: grid==CU-count capped occupancy at 8
// waves/CU and serialized the load-issue and MFMA phases). LDS 56KB/block
// (2x fits in 160KB); acc[4][6] = 96 acc regs/wave keeps 16 waves/CU within
// register budget. Same proven 2-deep counted-vmcnt pipeline + 0-conflict
// swizzle + XCD-chunked block swizzle. vmcnt(3): threads with 4 loads/stage
// over-wait one of the new stage's loads (issued first, long since back).
// MODE 0: store bf16. MODE 1: RMW bf16.
template <int MODE>
__global__ __launch_bounds__(512, 2)
void gemm192(const bf16* __restrict__ A1, int S1, int K1,
             const bf16* __restrict__ A2, int S2,
             const bf16* __restrict__ BT, int ldb,
             bf16* __restrict__ OUT, int Nn, int Ktot, int nbx) {
    __shared__ __align__(16) unsigned short lA[2][256 * 32];   // 2 x 16 KB
    __shared__ __align__(16) unsigned short lB[2][192 * 32];   // 2 x 12 KB
    const int nblk = gridDim.x, qx = nblk >> 3, bid = blockIdx.x;
    const int wgid = (bid & 7) * qx + (bid >> 3);
    const int bx = wgid % nbx, by = wgid / nbx;
    const int bn = bx * 192, bm = by * 256;
    const int tid = threadIdx.x;
    const int wave = tid >> 6, lane = tid & 63;
    const int wr = wave >> 1, wc = wave & 1;
    const int l15 = lane & 15, lg = lane >> 4;
    const int swz = (lg ^ ((l15 >> 1) & 3)) * 8;

    f32x4 acc[4][6] = {};
    const int nkt = Ktot >> 5;

    // stage K-tile t: A 256x32 = 1024 chunks (2/thread); B 192x32 = 768
    // chunks (1/thread + 1 extra for tid<256, i.e. waves 0-3).
    auto stage = [&](int t, int buf) {
        const int k0 = t * 32;
        const bf16* Ab; int koff, stA;
        if (k0 < K1) { Ab = A1; koff = k0; stA = S1; }
        else         { Ab = A2; koff = k0 - K1; stA = S2; }
#pragma unroll
        for (int u = 0; u < 2; ++u) {
            const int c = u * 512 + tid;
            const int r = c >> 2, s = c & 3;
            const int sc = (s ^ ((r >> 1) & 3)) * 8;
            const bf16* ga = Ab + (size_t)(bm + r) * stA + koff + sc;
            __builtin_amdgcn_global_load_lds((const GLOBAL_AS void*)ga,
                (LDS_AS void*)&lA[buf][(u * 512 + wave * 64) * 8], 16, 0, 0);
        }
        {
            const int c = tid;
            const int r = c >> 2, s = c & 3;
            const int sc = (s ^ ((r >> 1) & 3)) * 8;
            const bf16* gb = BT + (size_t)(bn + r) * ldb + k0 + sc;
            __builtin_amdgcn_global_load_lds((const GLOBAL_AS void*)gb,
                (LDS_AS void*)&lB[buf][(wave * 64) * 8], 16, 0, 0);
        }
        if (tid < 256) {
            const int c = 512 + tid;
            const int r = c >> 2, s = c & 3;
            const int sc = (s ^ ((r >> 1) & 3)) * 8;
            const bf16* gb = BT + (size_t)(bn + r) * ldb + k0 + sc;
            __builtin_amdgcn_global_load_lds((const GLOBAL_AS void*)gb,
                (LDS_AS void*)&lB[buf][(512 + wave * 64) * 8], 16, 0, 0);
        }
    };

    stage(0, 0);

    for (int t = 0; t < nkt; ++t) {
        const int rb = t & 1;
        if (t + 1 < nkt) {
            stage(t + 1, rb ^ 1);
            asm volatile("s_waitcnt vmcnt(3)" ::: "memory");
        } else {
            asm volatile("s_waitcnt vmcnt(0)" ::: "memory");
        }
        __builtin_amdgcn_s_barrier();
        __builtin_amdgcn_sched_barrier(0);

        bf16x8 af[4];
#pragma unroll
        for (int mi = 0; mi < 4; ++mi) {
            const int r = wr * 64 + mi * 16 + l15;
            af[mi] = *reinterpret_cast<const bf16x8*>(&lA[rb][r * 32 + swz]);
        }
        __builtin_amdgcn_s_setprio(1);
#pragma unroll
        for (int ni = 0; ni < 6; ++ni) {
            const int r = wc * 96 + ni * 16 + l15;
            bf16x8 bq = *reinterpret_cast<const bf16x8*>(&lB[rb][r * 32 + swz]);
#pragma unroll
            for (int mi = 0; mi < 4; ++mi)
                acc[mi][ni] = __builtin_amdgcn_mfma_f32_16x16x32_bf16(af[mi], bq, acc[mi][ni], 0, 0, 0);
        }
        __builtin_amdgcn_s_setprio(0);
        __builtin_amdgcn_sched_barrier(0);
        __builtin_amdgcn_s_barrier();
    }

    unsigned short* O = (unsigned short*)OUT;
#pragma unroll
    for (int mi = 0; mi < 4; ++mi)
#pragma unroll
        for (int ni = 0; ni < 6; ++ni) {
            const int r0 = bm + wr * 64 + mi * 16 + lg * 4;
            const int c0 = bn + wc * 96 + ni * 16 + l15;
#pragma unroll
            for (int i = 0; i < 4; ++i) {
                size_t idx = (size_t)(r0 + i) * Nn + c0;
                float v = acc[mi][ni][i];
                if (MODE == 1) v += bfu(O[idx]);
                O[idx] = fbf(v);
            }
        }
}

// ---------------------------------------------------------------------------
// bias + LN + GELU over bf16 partials; wave per row. grid N/4.
__global__ __launch_bounds__(256)
void ln_gelu_k(const bf16* __restrict__ ACCb, const float* __restrict__ bias,
               const float* __restrict__ g, const float* __restrict__ b,
               bf16* __restrict__ hout) {
    const int wave = threadIdx.x >> 6, lane = threadIdx.x & 63;
    const int n = blockIdx.x * 4 + wave;
    const unsigned short* Ab = (const unsigned short*)ACCb;
    float x[12];
    float s = 0.f, ss = 0.f;
#pragma unroll
    for (int j = 0; j < 12; ++j) {
        int c = lane + j * 64;
        x[j] = bfu(Ab[(size_t)n * DIM + c]) + bias[c];
        s += x[j]; ss += x[j] * x[j];
    }
#pragma unroll
    for (int m = 1; m < 64; m <<= 1) { s += __shfl_xor(s, m, 64); ss += __shfl_xor(ss, m, 64); }
    const float mean = s * (1.f / DIM);
    const float var = ss * (1.f / DIM) - mean * mean;
    const float rstd = rsqrtf(var + 1e-5f);
#pragma unroll
    for (int j = 0; j < 12; ++j) {
        int c = lane + j * 64;
        float y = (x[j] - mean) * rstd * g[c] + b[c];
        hout[(size_t)n * DIM + c] = __float2bfloat16(gelu_f(y));
    }
}

// ---------------------------------------------------------------------------
__global__ __launch_bounds__(256)
void gate_k(const bf16* __restrict__ G1, const float* __restrict__ bg1,
            const float* __restrict__ Wg2, const float* __restrict__ bg2,
            float* __restrict__ gate) {
    const int wave = threadIdx.x >> 6, lane = threadIdx.x & 63;
    const int n = blockIdx.x * 4 + wave;
    const unsigned short* G = (const unsigned short*)G1;
    float acc = 0.f;
#pragma unroll
    for (int j = 0; j < 6; ++j) {
        int c = lane + j * 64;
        float xv = bfu(G[(size_t)n * 384 + c]) + bg1[c];
        acc += gelu_f(xv) * Wg2[c];
    }
#pragma unroll
    for (int m = 1; m < 64; m <<= 1) acc += __shfl_xor(acc, m, 64);
    if (lane == 0) gate[n] = acc + bg2[0];
}

// ---------------------------------------------------------------------------
__device__ __forceinline__ int lower_bound_ng(const int* ng, int key) {
    int lo = 0, hi = N_NODES;
    while (lo < hi) { int mid = (lo + hi) >> 1; if (ng[mid] < key) lo = mid + 1; else hi = mid; }
    return lo;
}

__global__ __launch_bounds__(256)
void seg_stats_k(const float* __restrict__ gate, const int* __restrict__ ng,
                 float* __restrict__ gmax, float* __restrict__ gden) {
    __shared__ float red[256];
    const int b = blockIdx.x, t = threadIdx.x;
    const int start = lower_bound_ng(ng, b), end = lower_bound_ng(ng, b + 1);
    float m = -1e30f;
    for (int n = start + t; n < end; n += 256) m = fmaxf(m, gate[n]);
    red[t] = m; __syncthreads();
    for (int s = 128; s > 0; s >>= 1) { if (t < s) red[t] = fmaxf(red[t], red[t + s]); __syncthreads(); }
    const float gm = red[0]; __syncthreads();
    float ssum = 0.f;
    for (int n = start + t; n < end; n += 256) ssum += expf(gate[n] - gm);
    red[t] = ssum; __syncthreads();
    for (int s = 128; s > 0; s >>= 1) { if (t < s) red[t] += red[t + s]; __syncthreads(); }
    if (t == 0) { gmax[b] = gm; gden[b] = fmaxf(red[0], 1e-30f); }
}

__global__ __launch_bounds__(768)
void pool_k(const bf16* __restrict__ h, const float* __restrict__ gate,
            const int* __restrict__ ng, const float* __restrict__ gmax,
            const float* __restrict__ gden, float* __restrict__ grep) {
    const int b = blockIdx.x, c = threadIdx.x;
    const int start = lower_bound_ng(ng, b), end = lower_bound_ng(ng, b + 1);
    const float gm = gmax[b], inv = 1.0f / gden[b];
    const unsigned short* hv = (const unsigned short*)h;
    float a0 = 0.f, a1 = 0.f;
    int n = start;
    for (; n + 1 < end; n += 2) {
        float w0 = expf(gate[n] - gm) * inv;
        float w1 = expf(gate[n + 1] - gm) * inv;
        a0 += w0 * bfu(hv[(size_t)n * DIM + c]);
        a1 += w1 * bfu(hv[(size_t)(n + 1) * DIM + c]);
    }
    if (n < end) a0 += expf(gate[n] - gm) * inv * bfu(hv[(size_t)n * DIM + c]);
    grep[(size_t)b * DIM + c] = a0 + a1;
}

// ---------------------------------------------------------------------------
__global__ __launch_bounds__(512)
void cls_k(const float* __restrict__ grep, const float* __restrict__ Wc1,
           const float* __restrict__ bc1, const float* __restrict__ lng,
           const float* __restrict__ lnb, const float* __restrict__ Wc2,
           const float* __restrict__ bc2, float* __restrict__ out) {
    __shared__ float gr[DIM];
    __shared__ float red[512];
    const int b = blockIdx.x, j = threadIdx.x;
    for (int c = j; c < DIM; c += 512) gr[c] = grep[(size_t)b * DIM + c];
    __syncthreads();
    float a = bc1[j];
#pragma unroll 4
    for (int k = 0; k < DIM; ++k) a = fmaf(gr[k], Wc1[(size_t)k * 512 + j], a);
    red[j] = a; __syncthreads();
    for (int s = 256; s > 0; s >>= 1) { if (j < s) red[j] += red[j + s]; __syncthreads(); }
    const float mean = red[0] * (1.f / 512.f);
    __syncthreads();
    red[j] = (a - mean) * (a - mean); __syncthreads();
    for (int s = 256; s > 0; s >>= 1) { if (j < s) red[j] += red[j + s]; __syncthreads(); }
    const float rstd = rsqrtf(red[0] * (1.f / 512.f) + 1e-5f);
    __syncthreads();
    const float z = gelu_f((a - mean) * rstd * lng[j] + lnb[j]);
    red[j] = z * Wc2[2 * j + 0]; __syncthreads();
    for (int s = 256; s > 0; s >>= 1) { if (j < s) red[j] += red[j + s]; __syncthreads(); }
    const float l0 = red[0] + bc2[0];
    __syncthreads();
    red[j] = z * Wc2[2 * j + 1]; __syncthreads();
    for (int s = 256; s > 0; s >>= 1) { if (j < s) red[j] += red[j + s]; __syncthreads(); }
    if (j == 0) {
        const float l1 = red[0] + bc2[1];
        const float mx = fmaxf(l0, l1);
        const float lse = mx + logf(expf(l0 - mx) + expf(l1 - mx));
        out[2 * b + 0] = l0 - lse;
        out[2 * b + 1] = l1 - lse;
    }
}

// ---------------------------------------------------------------------------
extern "C" void kernel_launch(void* const* d_in, const int* in_sizes, int n_in,
                              void* d_out, int out_size, void* d_ws, size_t ws_size,
                              hipStream_t stream) {
    const float* type_vec = (const float*)d_in[0];
    const float* code_vec = (const float*)d_in[1];
    const float* W_in     = (const float*)d_in[2];
    const float* b_in     = (const float*)d_in[3];
    const float* ln_in_g  = (const float*)d_in[4];
    const float* ln_in_b  = (const float*)d_in[5];
    const float* W_rel    = (const float*)d_in[6];
    const float* W_loop   = (const float*)d_in[7];
    const float* rgcn_bias= (const float*)d_in[8];
    const float* ln_g     = (const float*)d_in[9];
    const float* ln_b     = (const float*)d_in[10];
    const float* Wg1      = (const float*)d_in[11];
    const float* bg1      = (const float*)d_in[12];
    const float* Wg2      = (const float*)d_in[13];
    const float* bg2      = (const float*)d_in[14];
    const float* Wc1      = (const float*)d_in[15];
    const float* bc1      = (const float*)d_in[16];
    const float* ln_c_g   = (const float*)d_in[17];
    const float* ln_c_b   = (const float*)d_in[18];
    const float* Wc2      = (const float*)d_in[19];
    const float* bc2      = (const float*)d_in[20];
    const int* src        = (const int*)d_in[21];
    const int* dst        = (const int*)d_in[22];
    const int* etype      = (const int*)d_in[23];
    const int* node_graph = (const int*)d_in[24];

    char* ws = (char*)d_ws;

    // layout: byte-identical to round-11 (big path decision must match).
    auto lay = [&](int nc, bool doAssign,
                   bf16*& h_bf, bf16*& ACCb, bf16*& WstL, int*& rp2, int*& cur2,
                   unsigned short*& eidx, float*& gate, float*& gmax, float*& gden,
                   float*& grep, bf16*& AGG) -> size_t {
        size_t off = 0;
        auto alloc = [&](size_t sz) { size_t r = off; off = (off + sz + 255) & ~(size_t)255; return r; };
        size_t oH   = alloc((size_t)N_NODES * DIM * 2);
        size_t oAC  = alloc((size_t)N_NODES * DIM * 2);
        size_t oWL  = alloc((size_t)DIM * KSTACK * 2);
        size_t oRP  = alloc((size_t)(NKEY + 1) * 4);
        size_t oCU  = alloc((size_t)NKEY * 4);
        size_t oEI  = alloc((size_t)N_EDGES * 2);
        size_t oGA  = alloc((size_t)N_NODES * 4);
        size_t oGM  = alloc(256);
        size_t oGD  = alloc(256);
        size_t oGR  = alloc((size_t)NGR * DIM * 4);
        size_t oAG  = alloc((size_t)N_NODES * nc * DIM * 2);
        if (doAssign) {
            h_bf = (bf16*)(ws + oH);   ACCb = (bf16*)(ws + oAC);
            WstL = (bf16*)(ws + oWL);  rp2  = (int*)(ws + oRP);
            cur2 = (int*)(ws + oCU);   eidx = (unsigned short*)(ws + oEI);
            gate = (float*)(ws + oGA); gmax = (float*)(ws + oGM);
            gden = (float*)(ws + oGD); grep = (float*)(ws + oGR);
            AGG  = (bf16*)(ws + oAG);
        }
        return off;
    };

    bf16 *h_bf, *ACCb, *WstL, *AGG; int *rp2, *cur2; unsigned short* eidx;
    float *gate, *gmax, *gden, *grep;
    bf16 *d0=nullptr,*d1=nullptr,*d2=nullptr,*d3=nullptr; int *d4=nullptr,*d5=nullptr;
    unsigned short* d6=nullptr; float *d7=nullptr,*d8=nullptr,*d9=nullptr,*d10=nullptr;
    const bool big = ws_size >= lay(8, false, d0,d1,d2,d4,d5,d6,d7,d8,d9,d10,d3);
    const int nc = big ? 8 : 4;
    lay(nc, true, h_bf, ACCb, WstL, rp2, cur2, eidx, gate, gmax, gden, grep, AGG);

    // AGG-region overlays
    bf16* Xbf  = AGG;                                             // [N][800]
    bf16* WinT = (bf16*)((char*)AGG + (size_t)N_NODES * KIN * 2); // [768][800]
    bf16* G1   = AGG;                                             // [N][384] bf16 at gate time

    const int AGW = nc * DIM;

    // --- input projection (X/WIN overlay AGG; dead before gathers)
    tcast_k<<<dim3(25, 24), 256, 0, stream>>>(W_in, WinT, 784, DIM, KIN, KIN);
    concat_k<<<N_NODES, 256, 0, stream>>>(type_vec, code_vec, Xbf);
    gemm192<0><<<512, 512, 0, stream>>>(Xbf, KIN, KIN, Xbf, KIN, WinT, KIN, ACCb, DIM, KIN, 4);
    ln_gelu_k<<<N_NODES / 4, 256, 0, stream>>>(ACCb, b_in, ln_in_g, ln_in_b, h_bf);

    // --- (dst,type) CSR build
    hipMemsetAsync(cur2, 0, (size_t)NKEY * 4, stream);
    hist2_k<<<N_EDGES / 256, 256, 0, stream>>>(dst, etype, cur2);
    scan2_k<<<1, 1024, 0, stream>>>(cur2, rp2);
    place2_k<<<N_EDGES / 256, 256, 0, stream>>>(src, dst, etype, cur2, eidx);

    // --- RGCN layers
    for (int l = 0; l < 3; ++l) {
        wprep_l_k<<<dim3(24, 24, 9), 256, 0, stream>>>(
            W_rel + (size_t)l * 8 * DIM * DIM, W_loop + (size_t)l * DIM * DIM, WstL);
        if (nc == 8) {
            gather8<8><<<N_NODES / 4, 256, 0, stream>>>(h_bf, rp2, eidx, AGG, 0, AGW, 0);
            gemm192<0><<<512, 512, 0, stream>>>(
                h_bf, DIM, DIM, AGG, AGW, WstL, KSTACK, ACCb, DIM, KSTACK, 4);
        } else {
            gather8<4><<<N_NODES / 4, 256, 0, stream>>>(h_bf, rp2, eidx, AGG, 0, AGW, 0);
            gemm192<0><<<512, 512, 0, stream>>>(
                h_bf, DIM, DIM, AGG, AGW, WstL, KSTACK, ACCb, DIM, DIM + 4 * DIM, 4);
            gather8<4><<<N_NODES / 4, 256, 0, stream>>>(h_bf, rp2, eidx, AGG, 4, AGW, 0);
            gemm192<1><<<512, 512, 0, stream>>>(
                AGG, AGW, AGW, AGG, AGW, WstL + (size_t)DIM * 5, KSTACK, ACCb, DIM, 4 * DIM, 4);
        }
        ln_gelu_k<<<N_NODES / 4, 256, 0, stream>>>(ACCb, rgcn_bias + l * DIM, ln_g + l * DIM,
                                                   ln_b + l * DIM, h_bf);
    }

    // --- global attention pooling (G1/Wg1T overlay AGG region, AGG dead)
    bf16* Wg1T = (bf16*)((char*)AGG + 60 * 1024 * 1024);
    tcast_k<<<dim3(24, 12), 256, 0, stream>>>(Wg1, Wg1T, DIM, 384, DIM, DIM);
    gemm192<0><<<256, 512, 0, stream>>>(h_bf, DIM, DIM, h_bf, DIM, Wg1T, DIM, G1, 384, DIM, 2);
    gate_k<<<N_NODES / 4, 256, 0, stream>>>(G1, bg1, Wg2, bg2, gate);
    seg_stats_k<<<NGR, 256, 0, stream>>>(gate, node_graph, gmax, gden);
    pool_k<<<NGR, 768, 0, stream>>>(h_bf, gate, node_graph, gmax, gden, grep);

    // --- classifier head
    cls_k<<<NGR, 512, 0, stream>>>(grep, Wc1, bc1, ln_c_g, ln_c_b, Wc2, bc2, (float*)d_out);
}

// Round 16
// 2457.252 us; speedup vs baseline: 1.1475x; 1.1475x over previous
//
#include <hip/hip_runtime.h>
#include <hip/hip_bf16.h>

typedef __hip_bfloat16 bf16;
typedef __attribute__((ext_vector_type(8))) __bf16 bf16x8;
typedef __attribute__((ext_vector_type(4))) float f32x4;

#define N_NODES 32768
#define N_EDGES 262144
#define DIM 768
#define NGR 64
#define KIN 800     // 784 padded to 32
#define KSTACK 6912 // self(768) + 8*768
#define NKEY (N_NODES * 8)

#define GLOBAL_AS __attribute__((address_space(1)))
#define LDS_AS __attribute__((address_space(3)))

__device__ __forceinline__ float gelu_f(float x) {
    return 0.5f * x * (1.0f + erff(x * 0.70710678118654752f));
}
__device__ __forceinline__ float bfu(unsigned short v) {
    union { unsigned u; float f; } x; x.u = (unsigned)v << 16; return x.f;
}
__device__ __forceinline__ unsigned short fbf(float f) {
    bf16 t = __float2bfloat16(f); return *(unsigned short*)&t;
}

// ---------------------------------------------------------------------------
// Transpose + cast fp32 [I][O] -> bf16 [O][ostride], zero-pad i in [I,Ipad)
__global__ __launch_bounds__(256)
void tcast_k(const float* __restrict__ in, bf16* __restrict__ out, int I, int O,
             int Ipad, int ostride) {
    __shared__ float t[32][33];
    const int i0 = blockIdx.x * 32, o0 = blockIdx.y * 32;
    const int tx = threadIdx.x & 31, ty = threadIdx.x >> 5;
#pragma unroll
    for (int q = 0; q < 4; ++q) {
        int i = i0 + ty + q * 8, o = o0 + tx;
        t[ty + q * 8][tx] = (i < I) ? in[(size_t)i * O + o] : 0.0f;
    }
    __syncthreads();
#pragma unroll
    for (int q = 0; q < 4; ++q) {
        int o = o0 + ty + q * 8, i = i0 + tx;
        if (i < Ipad) out[(size_t)o * ostride + i] = __float2bfloat16(t[tx][ty + q * 8]);
    }
}

// ---------------------------------------------------------------------------
// Per-layer weights -> WstL[768 out][6912 K], K order: [self | r0..r7]. grid(24,24,9)
__global__ __launch_bounds__(256)
void wprep_l_k(const float* __restrict__ Wrel_l, const float* __restrict__ Wloop_l,
               bf16* __restrict__ WstL) {
    __shared__ float t[32][33];
    const int q = blockIdx.z;
    const float* in = (q < 8) ? Wrel_l + (size_t)q * DIM * DIM : Wloop_l;
    bf16* out = WstL + (q < 8 ? (q + 1) * DIM : 0);
    const int i0 = blockIdx.x * 32, o0 = blockIdx.y * 32;
    const int tx = threadIdx.x & 31, ty = threadIdx.x >> 5;
#pragma unroll
    for (int qq = 0; qq < 4; ++qq)
        t[ty + qq * 8][tx] = in[(size_t)(i0 + ty + qq * 8) * DIM + o0 + tx];
    __syncthreads();
#pragma unroll
    for (int qq = 0; qq < 4; ++qq)
        out[(size_t)(o0 + ty + qq * 8) * KSTACK + i0 + tx] =
            __float2bfloat16(t[tx][ty + qq * 8]);
}

// ---------------------------------------------------------------------------
__global__ __launch_bounds__(256)
void concat_k(const float* __restrict__ tv, const float* __restrict__ cv, bf16* __restrict__ X) {
    const int n = blockIdx.x;
    for (int c = threadIdx.x; c < KIN; c += 256) {
        float v = 0.0f;
        if (c < 16) v = tv[(size_t)n * 16 + c];
        else if (c < 784) v = cv[(size_t)n * DIM + (c - 16)];
        X[(size_t)n * KIN + c] = __float2bfloat16(v);
    }
}

// ---------------------------------------------------------------------------
// CSR build over key = dst*8 + type. deg aliased into cur.
__global__ __launch_bounds__(256)
void hist2_k(const int* __restrict__ dst, const int* __restrict__ et, int* __restrict__ cur) {
    int e = blockIdx.x * 256 + threadIdx.x;
    if (e < N_EDGES) atomicAdd(&cur[dst[e] * 8 + et[e]], 1);
}

__global__ __launch_bounds__(1024)
void scan2_k(int* __restrict__ cur, int* __restrict__ rp) {
    __shared__ int part[1024];
    const int t = threadIdx.x;
    const int base_i = t * 256;
    int s = 0;
    for (int i = 0; i < 256; ++i) s += cur[base_i + i];
    part[t] = s; __syncthreads();
    for (int st = 1; st < 1024; st <<= 1) {
        int v = (t >= st) ? part[t - st] : 0;
        __syncthreads();
        part[t] += v;
        __syncthreads();
    }
    int run = part[t] - s;
    for (int i = 0; i < 256; ++i) {
        int d = cur[base_i + i];
        rp[base_i + i] = run; cur[base_i + i] = run;
        run += d;
    }
    if (t == 1023) rp[NKEY] = run;
}

__global__ __launch_bounds__(256)
void place2_k(const int* __restrict__ src, const int* __restrict__ dst,
              const int* __restrict__ et, int* __restrict__ cur,
              int* __restrict__ eidx) {
    int e = blockIdx.x * 256 + threadIdx.x;
    if (e >= N_EDGES) return;
    int pos = atomicAdd(&cur[dst[e] * 8 + et[e]], 1);
    eidx[pos] = (et[e] << 16) | src[e];
}

// ---------------------------------------------------------------------------
// Gather-aggregate for NC relations [rbase, rbase+NC), exact CSR ranges.
// ushort4-vectorized (3 x 8B per lane per row). No atomics.
template <int NC>
__global__ __launch_bounds__(256)
void gather8(const bf16* __restrict__ h, const int* __restrict__ rp2,
             const int* __restrict__ eidx, bf16* __restrict__ AGG,
             int rbase, int ostride, int colbase) {
    const int wave = threadIdx.x >> 6, lane = threadIdx.x & 63;
    const int n = blockIdx.x * 4 + wave;
    const int c0 = 4 * lane;
    unsigned short* outrow = (unsigned short*)&AGG[(size_t)n * ostride + colbase];
    const int* bp = &rp2[n * 8 + rbase];
    for (int sel = 0; sel < NC; ++sel) {
        const int s = bp[sel], e = bp[sel + 1];
        float f[12];
#pragma unroll
        for (int j = 0; j < 12; ++j) f[j] = 0.f;
        for (int t = s; t < e; ++t) {
            const int srcn = eidx[t] & 0xffff;
            const unsigned short* hs = (const unsigned short*)&h[(size_t)srcn * DIM];
#pragma unroll
            for (int j = 0; j < 3; ++j) {
                ushort4 u = *(const ushort4*)&hs[c0 + j * 256];
                f[4 * j + 0] += bfu(u.x); f[4 * j + 1] += bfu(u.y);
                f[4 * j + 2] += bfu(u.z); f[4 * j + 3] += bfu(u.w);
            }
        }
#pragma unroll
        for (int j = 0; j < 3; ++j) {
            ushort4 o;
            o.x = fbf(f[4 * j + 0]); o.y = fbf(f[4 * j + 1]);
            o.z = fbf(f[4 * j + 2]); o.w = fbf(f[4 * j + 3]);
            *(ushort4*)&outrow[sel * DIM + c0 + j * 256] = o;
        }
    }
}

// ---------------------------------------------------------------------------
// gemm384: C[M,Nn](bf16) =/+= A[M,K] @ BT[Nn,K]^T. BM=256, BN=384, BK=32.
// Best-measured structure (round 12): 3-deep LDS pipeline with counted vmcnt
// (stage(t+2) issued at iter t, vmcnt(10) waits only stage(t)); 0-conflict
// source-side swizzle; XCD-chunked block swizzle; 8 waves as 4x2, acc[4][12].
// MODE 0: store bf16. MODE 1: RMW bf16.
template <int MODE>
__global__ __launch_bounds__(512, 2)
void gemm384(const bf16* __restrict__ A1, int S1, int K1,
             const bf16* __restrict__ A2, int S2,
             const bf16* __restrict__ BT, int ldb,
             bf16* __restrict__ OUT, int Nn, int Ktot, int nbx) {
    __shared__ __align__(16) unsigned short lA[3][256 * 32];
    __shared__ __align__(16) unsigned short lB[3][384 * 32];
    const int nblk = gridDim.x, qx = nblk >> 3, bid = blockIdx.x;
    const int wgid = (bid & 7) * qx + (bid >> 3);
    const int bx = wgid % nbx, by = wgid / nbx;
    const int bn = bx * 384, bm = by * 256;
    const int tid = threadIdx.x;
    const int wave = tid >> 6, lane = tid & 63;
    const int wr = wave >> 1, wc = wave & 1;
    const int l15 = lane & 15, lg = lane >> 4;
    const int swz = (lg ^ ((l15 >> 1) & 3)) * 8;

    f32x4 acc[4][12] = {};
    const int nkt = Ktot >> 5;

    // stage K-tile t into buffer buf: 2 A-loads + 3 B-loads per thread
    auto stage = [&](int t, int buf) {
        const int k0 = t * 32;
        const bf16* Ab; int koff, stA;
        if (k0 < K1) { Ab = A1; koff = k0; stA = S1; }
        else         { Ab = A2; koff = k0 - K1; stA = S2; }
#pragma unroll
        for (int u = 0; u < 2; ++u) {            // A: 256x32 = 1024 chunks
            const int c = u * 512 + tid;
            const int r = c >> 2, s = c & 3;
            const int sc = (s ^ ((r >> 1) & 3)) * 8;
            const bf16* ga = Ab + (size_t)(bm + r) * stA + koff + sc;
            __builtin_amdgcn_global_load_lds((const GLOBAL_AS void*)ga,
                (LDS_AS void*)&lA[buf][(u * 512 + wave * 64) * 8], 16, 0, 0);
        }
#pragma unroll
        for (int u = 0; u < 3; ++u) {            // B: 384x32 = 1536 chunks
            const int c = u * 512 + tid;
            const int r = c >> 2, s = c & 3;
            const int sc = (s ^ ((r >> 1) & 3)) * 8;
            const bf16* gb = BT + (size_t)(bn + r) * ldb + k0 + sc;
            __builtin_amdgcn_global_load_lds((const GLOBAL_AS void*)gb,
                (LDS_AS void*)&lB[buf][(u * 512 + wave * 64) * 8], 16, 0, 0);
        }
    };

    stage(0, 0);
    if (nkt > 1) stage(1, 1);

    int rb = 0;
    for (int t = 0; t < nkt; ++t) {
        if (t + 2 < nkt) {
            int sb = rb + 2; if (sb >= 3) sb -= 3;
            stage(t + 2, sb);
            asm volatile("s_waitcnt vmcnt(10)" ::: "memory");
        } else if (t + 1 < nkt) {
            asm volatile("s_waitcnt vmcnt(5)" ::: "memory");
        } else {
            asm volatile("s_waitcnt vmcnt(0)" ::: "memory");
        }
        __builtin_amdgcn_s_barrier();
        __builtin_amdgcn_sched_barrier(0);

        bf16x8 af[4];
#pragma unroll
        for (int mi = 0; mi < 4; ++mi) {
            const int r = wr * 64 + mi * 16 + l15;
            af[mi] = *reinterpret_cast<const bf16x8*>(&lA[rb][r * 32 + swz]);
        }
        __builtin_amdgcn_s_setprio(1);
#pragma unroll
        for (int ni = 0; ni < 12; ++ni) {
            const int r = wc * 192 + ni * 16 + l15;
            bf16x8 bq = *reinterpret_cast<const bf16x8*>(&lB[rb][r * 32 + swz]);
#pragma unroll
            for (int mi = 0; mi < 4; ++mi)
                acc[mi][ni] = __builtin_amdgcn_mfma_f32_16x16x32_bf16(af[mi], bq, acc[mi][ni], 0, 0, 0);
        }
        __builtin_amdgcn_s_setprio(0);
        __builtin_amdgcn_sched_barrier(0);
        __builtin_amdgcn_s_barrier();

        rb = (rb == 2) ? 0 : rb + 1;
    }

    unsigned short* O = (unsigned short*)OUT;
#pragma unroll
    for (int mi = 0; mi < 4; ++mi)
#pragma unroll
        for (int ni = 0; ni < 12; ++ni) {
            const int r0 = bm + wr * 64 + mi * 16 + lg * 4;
            const int c0 = bn + wc * 192 + ni * 16 + l15;
#pragma unroll
            for (int i = 0; i < 4; ++i) {
                size_t idx = (size_t)(r0 + i) * Nn + c0;
                float v = acc[mi][ni][i];
                if (MODE == 1) v += bfu(O[idx]);
                O[idx] = fbf(v);
            }
        }
}

// ---------------------------------------------------------------------------
// Fused bias + LayerNorm + GELU over bf16 partials; wave per row. grid N/4.
__global__ __launch_bounds__(256)
void ln_gelu_k(const bf16* __restrict__ ACCb, const float* __restrict__ bias,
               const float* __restrict__ g, const float* __restrict__ b,
               bf16* __restrict__ hout) {
    const int wave = threadIdx.x >> 6, lane = threadIdx.x & 63;
    const int n = blockIdx.x * 4 + wave;
    const unsigned short* Ab = (const unsigned short*)ACCb;
    float x[12];
    float s = 0.f, ss = 0.f;
#pragma unroll
    for (int j = 0; j < 12; ++j) {
        int c = lane + j * 64;
        x[j] = bfu(Ab[(size_t)n * DIM + c]) + bias[c];
        s += x[j]; ss += x[j] * x[j];
    }
#pragma unroll
    for (int m = 1; m < 64; m <<= 1) { s += __shfl_xor(s, m, 64); ss += __shfl_xor(ss, m, 64); }
    const float mean = s * (1.f / DIM);
    const float var = ss * (1.f / DIM) - mean * mean;
    const float rstd = rsqrtf(var + 1e-5f);
#pragma unroll
    for (int j = 0; j < 12; ++j) {
        int c = lane + j * 64;
        float y = (x[j] - mean) * rstd * g[c] + b[c];
        hout[(size_t)n * DIM + c] = __float2bfloat16(gelu_f(y));
    }
}

// ---------------------------------------------------------------------------
// gate from bf16 G1: gate[n] = gelu(G1[n,:]+bg1) . Wg2 + bg2
__global__ __launch_bounds__(256)
void gate_k(const bf16* __restrict__ G1, const float* __restrict__ bg1,
            const float* __restrict__ Wg2, const float* __restrict__ bg2,
            float* __restrict__ gate) {
    const int wave = threadIdx.x >> 6, lane = threadIdx.x & 63;
    const int n = blockIdx.x * 4 + wave;
    const unsigned short* G = (const unsigned short*)G1;
    float acc = 0.f;
#pragma unroll
    for (int j = 0; j < 6; ++j) {
        int c = lane + j * 64;
        float xv = bfu(G[(size_t)n * 384 + c]) + bg1[c];
        acc += gelu_f(xv) * Wg2[c];
    }
#pragma unroll
    for (int m = 1; m < 64; m <<= 1) acc += __shfl_xor(acc, m, 64);
    if (lane == 0) gate[n] = acc + bg2[0];
}

// ---------------------------------------------------------------------------
__device__ __forceinline__ int lower_bound_ng(const int* ng, int key) {
    int lo = 0, hi = N_NODES;
    while (lo < hi) { int mid = (lo + hi) >> 1; if (ng[mid] < key) lo = mid + 1; else hi = mid; }
    return lo;
}

__global__ __launch_bounds__(256)
void seg_stats_k(const float* __restrict__ gate, const int* __restrict__ ng,
                 float* __restrict__ gmax, float* __restrict__ gden) {
    __shared__ float red[256];
    const int b = blockIdx.x, t = threadIdx.x;
    const int start = lower_bound_ng(ng, b), end = lower_bound_ng(ng, b + 1);
    float m = -1e30f;
    for (int n = start + t; n < end; n += 256) m = fmaxf(m, gate[n]);
    red[t] = m; __syncthreads();
    for (int s = 128; s > 0; s >>= 1) { if (t < s) red[t] = fmaxf(red[t], red[t + s]); __syncthreads(); }
    const float gm = red[0]; __syncthreads();
    float ssum = 0.f;
    for (int n = start + t; n < end; n += 256) ssum += expf(gate[n] - gm);
    red[t] = ssum; __syncthreads();
    for (int s = 128; s > 0; s >>= 1) { if (t < s) red[t] += red[t + s]; __syncthreads(); }
    if (t == 0) { gmax[b] = gm; gden[b] = fmaxf(red[0], 1e-30f); }
}

__global__ __launch_bounds__(768)
void pool_k(const bf16* __restrict__ h, const float* __restrict__ gate,
            const int* __restrict__ ng, const float* __restrict__ gmax,
            const float* __restrict__ gden, float* __restrict__ grep) {
    const int b = blockIdx.x, c = threadIdx.x;
    const int start = lower_bound_ng(ng, b), end = lower_bound_ng(ng, b + 1);
    const float gm = gmax[b], inv = 1.0f / gden[b];
    const unsigned short* hv = (const unsigned short*)h;
    float a0 = 0.f, a1 = 0.f;
    int n = start;
    for (; n + 1 < end; n += 2) {
        float w0 = expf(gate[n] - gm) * inv;
        float w1 = expf(gate[n + 1] - gm) * inv;
        a0 += w0 * bfu(hv[(size_t)n * DIM + c]);
        a1 += w1 * bfu(hv[(size_t)(n + 1) * DIM + c]);
    }
    if (n < end) a0 += expf(gate[n] - gm) * inv * bfu(hv[(size_t)n * DIM + c]);
    grep[(size_t)b * DIM + c] = a0 + a1;
}

// ---------------------------------------------------------------------------
__global__ __launch_bounds__(512)
void cls_k(const float* __restrict__ grep, const float* __restrict__ Wc1,
           const float* __restrict__ bc1, const float* __restrict__ lng,
           const float* __restrict__ lnb, const float* __restrict__ Wc2,
           const float* __restrict__ bc2, float* __restrict__ out) {
    __shared__ float gr[DIM];
    __shared__ float red[512];
    const int b = blockIdx.x, j = threadIdx.x;
    for (int c = j; c < DIM; c += 512) gr[c] = grep[(size_t)b * DIM + c];
    __syncthreads();
    float a = bc1[j];
#pragma unroll 4
    for (int k = 0; k < DIM; ++k) a = fmaf(gr[k], Wc1[(size_t)k * 512 + j], a);
    red[j] = a; __syncthreads();
    for (int s = 256; s > 0; s >>= 1) { if (j < s) red[j] += red[j + s]; __syncthreads(); }
    const float mean = red[0] * (1.f / 512.f);
    __syncthreads();
    red[j] = (a - mean) * (a - mean); __syncthreads();
    for (int s = 256; s > 0; s >>= 1) { if (j < s) red[j] += red[j + s]; __syncthreads(); }
    const float rstd = rsqrtf(red[0] * (1.f / 512.f) + 1e-5f);
    __syncthreads();
    const float z = gelu_f((a - mean) * rstd * lng[j] + lnb[j]);
    red[j] = z * Wc2[2 * j + 0]; __syncthreads();
    for (int s = 256; s > 0; s >>= 1) { if (j < s) red[j] += red[j + s]; __syncthreads(); }
    const float l0 = red[0] + bc2[0];
    __syncthreads();
    red[j] = z * Wc2[2 * j + 1]; __syncthreads();
    for (int s = 256; s > 0; s >>= 1) { if (j < s) red[j] += red[j + s]; __syncthreads(); }
    if (j == 0) {
        const float l1 = red[0] + bc2[1];
        const float mx = fmaxf(l0, l1);
        const float lse = mx + logf(expf(l0 - mx) + expf(l1 - mx));
        out[2 * b + 0] = l0 - lse;
        out[2 * b + 1] = l1 - lse;
    }
}

// ---------------------------------------------------------------------------
extern "C" void kernel_launch(void* const* d_in, const int* in_sizes, int n_in,
                              void* d_out, int out_size, void* d_ws, size_t ws_size,
                              hipStream_t stream) {
    const float* type_vec = (const float*)d_in[0];
    const float* code_vec = (const float*)d_in[1];
    const float* W_in     = (const float*)d_in[2];
    const float* b_in     = (const float*)d_in[3];
    const float* ln_in_g  = (const float*)d_in[4];
    const float* ln_in_b  = (const float*)d_in[5];
    const float* W_rel    = (const float*)d_in[6];
    const float* W_loop   = (const float*)d_in[7];
    const float* rgcn_bias= (const float*)d_in[8];
    const float* ln_g     = (const float*)d_in[9];
    const float* ln_b     = (const float*)d_in[10];
    const float* Wg1      = (const float*)d_in[11];
    const float* bg1      = (const float*)d_in[12];
    const float* Wg2      = (const float*)d_in[13];
    const float* bg2      = (const float*)d_in[14];
    const float* Wc1      = (const float*)d_in[15];
    const float* bc1      = (const float*)d_in[16];
    const float* ln_c_g   = (const float*)d_in[17];
    const float* ln_c_b   = (const float*)d_in[18];
    const float* Wc2      = (const float*)d_in[19];
    const float* bc2      = (const float*)d_in[20];
    const int* src        = (const int*)d_in[21];
    const int* dst        = (const int*)d_in[22];
    const int* etype      = (const int*)d_in[23];
    const int* node_graph = (const int*)d_in[24];

    char* ws = (char*)d_ws;

    auto lay = [&](int nc, bool doAssign,
                   bf16*& h_bf, bf16*& ACCb, bf16*& WstL, int*& rp2, int*& cur2,
                   int*& eidx, float*& gate, float*& gmax, float*& gden,
                   float*& grep, bf16*& AGG) -> size_t {
        size_t off = 0;
        auto alloc = [&](size_t sz) { size_t r = off; off = (off + sz + 255) & ~(size_t)255; return r; };
        size_t oH   = alloc((size_t)N_NODES * DIM * 2);
        size_t oAC  = alloc((size_t)N_NODES * DIM * 2);
        size_t oWL  = alloc((size_t)DIM * KSTACK * 2);
        size_t oRP  = alloc((size_t)(NKEY + 1) * 4);
        size_t oCU  = alloc((size_t)NKEY * 4);
        size_t oEI  = alloc((size_t)N_EDGES * 4);
        size_t oGA  = alloc((size_t)N_NODES * 4);
        size_t oGM  = alloc(256);
        size_t oGD  = alloc(256);
        size_t oGR  = alloc((size_t)NGR * DIM * 4);
        size_t oAG  = alloc((size_t)N_NODES * nc * DIM * 2);
        if (doAssign) {
            h_bf = (bf16*)(ws + oH);   ACCb = (bf16*)(ws + oAC);
            WstL = (bf16*)(ws + oWL);  rp2  = (int*)(ws + oRP);
            cur2 = (int*)(ws + oCU);   eidx = (int*)(ws + oEI);
            gate = (float*)(ws + oGA); gmax = (float*)(ws + oGM);
            gden = (float*)(ws + oGD); grep = (float*)(ws + oGR);
            AGG  = (bf16*)(ws + oAG);
        }
        return off;
    };

    bf16 *h_bf, *ACCb, *WstL, *AGG; int *rp2, *cur2, *eidx;
    float *gate, *gmax, *gden, *grep;
    bf16 *d0=nullptr,*d1=nullptr,*d2=nullptr,*d3=nullptr; int *d4=nullptr,*d5=nullptr,*d6=nullptr;
    float *d7=nullptr,*d8=nullptr,*d9=nullptr,*d10=nullptr;
    const bool big = ws_size >= lay(8, false, d0,d1,d2,d4,d5,d6,d7,d8,d9,d10,d3);
    const int nc = big ? 8 : 4;
    lay(nc, true, h_bf, ACCb, WstL, rp2, cur2, eidx, gate, gmax, gden, grep, AGG);

    // AGG-region overlays
    bf16* Xbf  = AGG;                                             // [N][800]
    bf16* WinT = (bf16*)((char*)AGG + (size_t)N_NODES * KIN * 2); // [768][800]
    bf16* G1   = AGG;                                             // [N][384] bf16 at gate time

    const int AGW = nc * DIM;

    // --- input projection (X/WIN overlay AGG; dead before gathers)
    tcast_k<<<dim3(25, 24), 256, 0, stream>>>(W_in, WinT, 784, DIM, KIN, KIN);
    concat_k<<<N_NODES, 256, 0, stream>>>(type_vec, code_vec, Xbf);
    gemm384<0><<<256, 512, 0, stream>>>(Xbf, KIN, KIN, Xbf, KIN, WinT, KIN, ACCb, DIM, KIN, 2);
    ln_gelu_k<<<N_NODES / 4, 256, 0, stream>>>(ACCb, b_in, ln_in_g, ln_in_b, h_bf);

    // --- (dst,type) CSR build
    hipMemsetAsync(cur2, 0, (size_t)NKEY * 4, stream);
    hist2_k<<<N_EDGES / 256, 256, 0, stream>>>(dst, etype, cur2);
    scan2_k<<<1, 1024, 0, stream>>>(cur2, rp2);
    place2_k<<<N_EDGES / 256, 256, 0, stream>>>(src, dst, etype, cur2, eidx);

    // --- RGCN layers
    for (int l = 0; l < 3; ++l) {
        wprep_l_k<<<dim3(24, 24, 9), 256, 0, stream>>>(
            W_rel + (size_t)l * 8 * DIM * DIM, W_loop + (size_t)l * DIM * DIM, WstL);
        if (nc == 8) {
            gather8<8><<<N_NODES / 4, 256, 0, stream>>>(h_bf, rp2, eidx, AGG, 0, AGW, 0);
            gemm384<0><<<256, 512, 0, stream>>>(
                h_bf, DIM, DIM, AGG, AGW, WstL, KSTACK, ACCb, DIM, KSTACK, 2);
        } else {
            gather8<4><<<N_NODES / 4, 256, 0, stream>>>(h_bf, rp2, eidx, AGG, 0, AGW, 0);
            gemm384<0><<<256, 512, 0, stream>>>(
                h_bf, DIM, DIM, AGG, AGW, WstL, KSTACK, ACCb, DIM, DIM + 4 * DIM, 2);
            gather8<4><<<N_NODES / 4, 256, 0, stream>>>(h_bf, rp2, eidx, AGG, 4, AGW, 0);
            gemm384<1><<<256, 512, 0, stream>>>(
                AGG, AGW, AGW, AGG, AGW, WstL + (size_t)DIM * 5, KSTACK, ACCb, DIM, 4 * DIM, 2);
        }
        ln_gelu_k<<<N_NODES / 4, 256, 0, stream>>>(ACCb, rgcn_bias + l * DIM, ln_g + l * DIM,
                                                   ln_b + l * DIM, h_bf);
    }

    // --- global attention pooling (G1/Wg1T overlay AGG region, AGG dead)
    bf16* Wg1T = (bf16*)((char*)AGG + 60 * 1024 * 1024);
    tcast_k<<<dim3(24, 12), 256, 0, stream>>>(Wg1, Wg1T, DIM, 384, DIM, DIM);
    gemm384<0><<<128, 512, 0, stream>>>(h_bf, DIM, DIM, h_bf, DIM, Wg1T, DIM, G1, 384, DIM, 1);
    gate_k<<<N_NODES / 4, 256, 0, stream>>>(G1, bg1, Wg2, bg2, gate);
    seg_stats_k<<<NGR, 256, 0, stream>>>(gate, node_graph, gmax, gden);
    pool_k<<<NGR, 768, 0, stream>>>(h_bf, gate, node_graph, gmax, gden, grep);

    // --- classifier head
    cls_k<<<NGR, 512, 0, stream>>>(grep, Wc1, bc1, ln_c_g, ln_c_b, Wc2, bc2, (float*)d_out);
}